// Round 1
// baseline (1926.086 us; speedup 1.0000x reference)
//
#include <hip/hip_runtime.h>
#include <cfloat>
#include <cmath>

#define DEV __device__ __forceinline__

constexpr int BB = 2, NN = 8192, KK = 16, CIN = 32, HH = 32, CO = 64, C2 = 128;
constexpr int BNTOT = BB * NN;        // 16384
constexpr int BNKROWS = BB * NN * KK; // 262144
constexpr float EPSF = 1e-6f;

// stats indices (doubles): [sum.., sumsq..] per group
constexpr int S_LSE1 = 0, S_LSE2 = 64, S_ATT1 = 128, S_ATT2 = 192, S_SHORT = 320, S_TOTAL = 576;
// scale/shift indices (floats): [scale.., shift..] per group
constexpr int SS_LSE1 = 0, SS_LSE2 = 64, SS_ATT1 = 128, SS_ATT2 = 192, SS_SHORT = 320, SS_TOTAL = 576;

// workspace layout (in floats)
constexpr size_t OFF_CP4   = 0;                                  // (x,y,z,sq) per point: 16384*4
constexpr size_t OFF_SE    = OFF_CP4 + (size_t)BNTOT * 4;        // se (B,N,K,10)
constexpr size_t OFF_XF    = OFF_SE + (size_t)BNKROWS * 10;      // mlp1 out (B,N,32)
constexpr size_t OFF_SHORT = OFF_XF + (size_t)BNTOT * HH;        // shortcut pre-BN (B,N,128)
constexpr size_t OFF_PRE1  = OFF_SHORT + (size_t)BNTOT * C2;     // att1 pre-BN (B,N,32)
constexpr size_t OFF_PRE2  = OFF_PRE1 + (size_t)BNTOT * HH;      // att2 pre-BN (B,N,64)
constexpr size_t OFF_SS    = OFF_PRE2 + (size_t)BNTOT * CO;      // scale/shift f32 x576
constexpr size_t OFF_STATS = OFF_SS + SS_TOTAL;                  // doubles x576 (float-offset is even -> 8B aligned)

// ---------------- K0: pack (x,y,z,sq) ----------------
__global__ __launch_bounds__(256) void k_prep(const float* __restrict__ coords,
                                              float4* __restrict__ cp4) {
#pragma clang fp contract(off)
    int i = blockIdx.x * 256 + threadIdx.x;
    if (i >= BNTOT) return;
    float x = coords[3 * i], y = coords[3 * i + 1], z = coords[3 * i + 2];
    float sq = (x * x + y * y) + z * z;   // match numpy sum order, no FMA
    cp4[i] = make_float4(x, y, z, sq);
}

// ---------------- K1: fused KNN + spatial encoding ----------------
// grid: 256 blocks (2 batches x 128), block: 256 threads.
// block handles 64 queries; wave w scans candidate range [w*2048, (w+1)*2048).
__global__ __launch_bounds__(256) void k_knn(const float4* __restrict__ cp4,
                                             float* __restrict__ se) {
#pragma clang fp contract(off)
    __shared__ __align__(16) float tile[4][512][4];
    __shared__ float md[4][64][16];
    __shared__ int   mi[4][64][16];

    int t = threadIdx.x;
    int b = blockIdx.x >> 7;
    int qbase = (blockIdx.x & 127) * 64;
    int ql = t & 63, part = t >> 6;
    int q = qbase + ql;
    const float4* cp = cp4 + (size_t)b * NN;
    float4 qc = cp[q];

    float dl[16];
    int il[16];
#pragma unroll
    for (int i = 0; i < 16; ++i) { dl[i] = FLT_MAX; il[i] = 0; }

    int cbase = part * 2048;
    for (int tb = 0; tb < 2048; tb += 512) {
        __syncthreads();
        for (int e = t; e < 2048; e += 256) {
            int p = e >> 9, j = e & 511;
            float4 v = cp[p * 2048 + tb + j];
            *(float4*)&tile[p][j][0] = v;
        }
        __syncthreads();
        for (int j = 0; j < 512; ++j) {
            float4 c = *(const float4*)&tile[part][j][0];
            float dot = (qc.x * c.x + qc.y * c.y) + qc.z * c.z;
            float d2 = (qc.w + c.w) - 2.0f * dot;   // exact jax/np expansion formula
            if (d2 < dl[15]) {
                float dk = d2; int jk = cbase + tb + j;
#pragma unroll
                for (int i = 0; i < 16; ++i) {
                    if (dk < dl[i]) {
                        float td = dl[i]; dl[i] = dk; dk = td;
                        int ti = il[i]; il[i] = jk; jk = ti;
                    }
                }
            }
        }
    }
    // publish partial lists
#pragma unroll
    for (int i = 0; i < 16; ++i) { md[part][ql][i] = dl[i]; mi[part][ql][i] = il[i]; }
    __syncthreads();

    if (t < 64) {  // wave 0 (part 0) merges parts 1..3 into its own list (stable by index)
        for (int p = 1; p < 4; ++p) {
#pragma unroll
            for (int i = 0; i < 16; ++i) {
                float d = md[p][t][i]; int jj = mi[p][t][i];
                if (d < dl[15]) {
                    float dk = d; int jk = jj;
#pragma unroll
                    for (int r = 0; r < 16; ++r) {
                        if (dk < dl[r]) {
                            float td = dl[r]; dl[r] = dk; dk = td;
                            int ti = il[r]; il[r] = jk; jk = ti;
                        }
                    }
                }
            }
        }
        // spatial encoding: [center(3), nbr(3), center-nbr(3), dist]
        float* sp = se + ((size_t)(b * NN + q) * KK) * 10;
#pragma unroll
        for (int k = 0; k < 16; ++k) {
            float4 nb = cp[il[k]];
            float dist = sqrtf(fmaxf(dl[k], 1e-12f));
            sp[k * 10 + 0] = qc.x; sp[k * 10 + 1] = qc.y; sp[k * 10 + 2] = qc.z;
            sp[k * 10 + 3] = nb.x; sp[k * 10 + 4] = nb.y; sp[k * 10 + 5] = nb.z;
            sp[k * 10 + 6] = qc.x - nb.x; sp[k * 10 + 7] = qc.y - nb.y; sp[k * 10 + 8] = qc.z - nb.z;
            sp[k * 10 + 9] = dist;
        }
    }
}

// ---------------- K2: mlp1 + shortcut linear + shortcut BN stats ----------------
// block: 128 threads (thread = output channel), handles 128 points; grid: 128 blocks.
__global__ __launch_bounds__(128) void k_feat(const float* __restrict__ feat,
                                              const float* __restrict__ Wm1, const float* __restrict__ bm1,
                                              const float* __restrict__ Wsh, const float* __restrict__ bsh,
                                              float* __restrict__ xf, float* __restrict__ short_pre,
                                              double* __restrict__ stats) {
    __shared__ float fl[32][33];
    int t = threadIdx.x;
    int pbase = blockIdx.x * 128;
    float wcol[32];
#pragma unroll
    for (int i = 0; i < 32; ++i) wcol[i] = Wsh[i * C2 + t];
    float wm[32];
    if (t < 32) {
#pragma unroll
        for (int i = 0; i < 32; ++i) wm[i] = Wm1[i * HH + t];
    }
    float bs = bsh[t];
    float bm = (t < 32) ? bm1[t] : 0.f;
    double s = 0.0, s2 = 0.0;

    for (int c0 = 0; c0 < 128; c0 += 32) {
        __syncthreads();
        for (int e = t; e < 1024; e += 128) {
            int p = e >> 5, i = e & 31;
            fl[p][i] = feat[(size_t)(pbase + c0 + p) * CIN + i];
        }
        __syncthreads();
        for (int p = 0; p < 32; ++p) {
            float acc = bs;
#pragma unroll
            for (int i = 0; i < 32; ++i) acc += fl[p][i] * wcol[i];
            int gp = pbase + c0 + p;
            short_pre[(size_t)gp * C2 + t] = acc;
            s += acc; s2 += (double)acc * acc;
            if (t < 32) {
                float xv = bm;
#pragma unroll
                for (int i = 0; i < 32; ++i) xv += fl[p][i] * wm[i];
                xf[(size_t)gp * HH + t] = xv >= 0.f ? xv : 0.2f * xv;
            }
        }
    }
    atomicAdd(&stats[S_SHORT + t], s);
    atomicAdd(&stats[S_SHORT + C2 + t], s2);
}

// ---------------- K3: lse1+lse2 linear BN stats (lin recomputed later) ----------------
// grid 256 x 256 threads; lane c<32 -> lse1 ch c, c>=32 -> lse2 ch c-32; 4 wave-groups stride rows.
__global__ __launch_bounds__(256) void k_lse_stats(const float* __restrict__ se,
                                                   const float* __restrict__ W1, const float* __restrict__ b1,
                                                   const float* __restrict__ W2, const float* __restrict__ b2,
                                                   double* __restrict__ stats) {
    int t = threadIdx.x;
    int c = t & 63, grp = t >> 6;
    int ch = c & 31; bool second = c >= 32;
    const float* W = second ? W2 : W1;
    float wcol[10];
#pragma unroll
    for (int d = 0; d < 10; ++d) wcol[d] = W[d * HH + ch];
    float bb = second ? b2[ch] : b1[ch];
    double s = 0.0, s2 = 0.0;
    int rbase = blockIdx.x * 1024;
    for (int r = grp; r < 1024; r += 4) {
        const float* sr = se + (size_t)(rbase + r) * 10;
        float acc = bb;
#pragma unroll
        for (int d = 0; d < 10; ++d) acc += sr[d] * wcol[d];
        s += acc; s2 += (double)acc * acc;
    }
    __shared__ double red[4][64][2];
    red[grp][c][0] = s; red[grp][c][1] = s2;
    __syncthreads();
    if (grp == 0) {
        for (int g = 1; g < 4; ++g) { s += red[g][c][0]; s2 += red[g][c][1]; }
        int base = second ? S_LSE2 : S_LSE1;
        atomicAdd(&stats[base + ch], s);
        atomicAdd(&stats[base + 32 + ch], s2);
    }
}

// ---------------- BN finalize helpers ----------------
DEV void fin_one(const double* stats, int sbase, int ch, int nch, double M,
                 const float* g, const float* be, float* ss, int ssbase) {
    double mean = stats[sbase + ch] / M;
    double var = stats[sbase + nch + ch] / M - mean * mean;
    double scale = (double)g[ch] / sqrt(var + (double)EPSF);
    double shift = (double)be[ch] - mean * scale;
    ss[ssbase + ch] = (float)scale;
    ss[ssbase + nch + ch] = (float)shift;
}

__global__ void k_fin_misc(const double* __restrict__ stats, float* __restrict__ ss,
                           const float* g1, const float* be1, const float* g2, const float* be2,
                           const float* gs, const float* bes) {
    int t = threadIdx.x;
    if (t < 32) fin_one(stats, S_LSE1, t, 32, (double)BNKROWS, g1, be1, ss, SS_LSE1);
    else if (t < 64) fin_one(stats, S_LSE2, t - 32, 32, (double)BNKROWS, g2, be2, ss, SS_LSE2);
    else if (t < 192) fin_one(stats, S_SHORT, t - 64, 128, (double)BNTOT, gs, bes, ss, SS_SHORT);
}

__global__ void k_fin_att(const double* __restrict__ stats, float* __restrict__ ss,
                          const float* g, const float* be, int sbase, int nch, int ssbase) {
    int t = threadIdx.x;
    if (t < nch) fin_one(stats, sbase, t, nch, (double)BNTOT, g, be, ss, ssbase);
}

// ---------------- K5/K7: fused LocSE + attentive pooling + MLP (pre-BN out + stats) ----------------
// grid 256 x 256 (4 waves); wave handles 16 points sequentially; lane = x1 channel (0..63).
template <int OUTC, bool SECOND>
__global__ __launch_bounds__(256) void k_att(const float* __restrict__ se,
                                             const float* __restrict__ featsrc,
                                             const float* __restrict__ Wlse, const float* __restrict__ blse,
                                             const float* __restrict__ Wlin,
                                             const float* __restrict__ Wmlp, const float* __restrict__ bmlp,
                                             const float* __restrict__ ss, int lse_ss, int feat_ss, int stat_base,
                                             float* __restrict__ preout, double* __restrict__ stats) {
    __shared__ __align__(16) float wlt[64][68];   // W_att_lin transposed, padded for b128 alignment
    __shared__ float wm[64][OUTC];
    __shared__ __align__(16) float x1[4][16][64];
    __shared__ float p1b[4][64];
    __shared__ double red[4][OUTC][2];

    int t = threadIdx.x, w = t >> 6, c = t & 63;
    for (int e = t; e < 4096; e += 256) wlt[e & 63][e >> 6] = Wlin[e];
    for (int e = t; e < 64 * OUTC; e += 256) wm[e / OUTC][e % OUTC] = Wmlp[e];

    float wf[10]; float bf = 0.f;
    if (c < 32) {   // fold BN scale/shift into the LocSE weights: relu(lin*sc+sh) = relu(se@(W*sc) + (b*sc+sh))
        float sc_ = ss[lse_ss + c], sh_ = ss[lse_ss + 32 + c];
#pragma unroll
        for (int d = 0; d < 10; ++d) wf[d] = Wlse[d * 32 + c] * sc_;
        bf = blse[c] * sc_ + sh_;
    }
    float fa = 1.f, fb = 0.f;
    if (SECOND && c >= 32) { fa = ss[feat_ss + (c - 32)]; fb = ss[feat_ss + 32 + (c - 32)]; }
    double s = 0.0, s2 = 0.0;
    __syncthreads();

    for (int i = 0; i < 16; ++i) {
        int p = blockIdx.x * 64 + w * 16 + i;
        float col[16];
        if (c < 32) {
            const float* sp = se + (size_t)p * (KK * 10);
#pragma unroll
            for (int k = 0; k < 16; ++k) {
                float acc = bf;
#pragma unroll
                for (int d = 0; d < 10; ++d) acc += sp[k * 10 + d] * wf[d];
                col[k] = fmaxf(acc, 0.f);
            }
        } else {
            float xv = featsrc[(size_t)p * 32 + (c - 32)];
            if (SECOND) xv = fmaxf(xv * fa + fb, 0.f);
#pragma unroll
            for (int k = 0; k < 16; ++k) col[k] = xv;
        }
#pragma unroll
        for (int k = 0; k < 16; ++k) x1[w][k][c] = col[k];

        // scores: s[k] = sum_d x1[k][d] * Wlin[d][c]   (x1 via b128 broadcast, wlt per-lane column)
        float scv[16];
#pragma unroll
        for (int k = 0; k < 16; ++k) scv[k] = 0.f;
        for (int dg = 0; dg < 16; ++dg) {
            float4 wv = *(const float4*)&wlt[c][dg * 4];
#pragma unroll
            for (int k = 0; k < 16; ++k) {
                float4 xv = *(const float4*)&x1[w][k][dg * 4];
                scv[k] += xv.x * wv.x + xv.y * wv.y + xv.z * wv.z + xv.w * wv.w;
            }
        }
        // softmax over k + weighted sum (lane owns its own x1 column in col[])
        float m = scv[0];
#pragma unroll
        for (int k = 1; k < 16; ++k) m = fmaxf(m, scv[k]);
        float sum = 0.f, p1 = 0.f;
#pragma unroll
        for (int k = 0; k < 16; ++k) { float e = __expf(scv[k] - m); sum += e; p1 += e * col[k]; }
        p1 /= sum;
        p1b[w][c] = p1;

        if (c < OUTC) {
            float acc = bmlp[c];
#pragma unroll
            for (int d = 0; d < 64; ++d) acc += p1b[w][d] * wm[d][c];
            preout[(size_t)p * OUTC + c] = acc;
            s += acc; s2 += (double)acc * acc;
        }
    }
    if (c < OUTC) { red[w][c][0] = s; red[w][c][1] = s2; }
    __syncthreads();
    if (t < OUTC) {
        double ts = red[0][t][0], ts2 = red[0][t][1];
        for (int g = 1; g < 4; ++g) { ts += red[g][t][0]; ts2 += red[g][t][1]; }
        atomicAdd(&stats[stat_base + t], ts);
        atomicAdd(&stats[stat_base + OUTC + t], ts2);
    }
}

// ---------------- K9: final mlp2 + shortcut BN + residual leaky + transposed write ----------------
__global__ __launch_bounds__(256) void k_out(const float* __restrict__ pre2,
                                             const float* __restrict__ short_pre,
                                             const float* __restrict__ W2, const float* __restrict__ b2,
                                             const float* __restrict__ ss, float* __restrict__ out) {
    __shared__ __align__(16) float w2[64][128];
    __shared__ float sc2[64], sh2[64], scs[128], shs[128], bb[128];
    int t = threadIdx.x;
    for (int e = t; e < 8192; e += 256) w2[e >> 7][e & 127] = W2[e];
    if (t < 64) { sc2[t] = ss[SS_ATT2 + t]; sh2[t] = ss[SS_ATT2 + 64 + t]; }
    if (t < 128) { scs[t] = ss[SS_SHORT + t]; shs[t] = ss[SS_SHORT + 128 + t]; bb[t] = b2[t]; }
    __syncthreads();

    int p = blockIdx.x * 256 + t;
    int b = p >> 13, n = p & 8191;
    const float* pr = pre2 + (size_t)p * 64;
    float xa[64];
#pragma unroll
    for (int c = 0; c < 64; c += 4) {
        float4 v = *(const float4*)&pr[c];
        xa[c + 0] = fmaxf(v.x * sc2[c + 0] + sh2[c + 0], 0.f);
        xa[c + 1] = fmaxf(v.y * sc2[c + 1] + sh2[c + 1], 0.f);
        xa[c + 2] = fmaxf(v.z * sc2[c + 2] + sh2[c + 2], 0.f);
        xa[c + 3] = fmaxf(v.w * sc2[c + 3] + sh2[c + 3], 0.f);
    }
    const float* shp = short_pre + (size_t)p * 128;
    for (int o = 0; o < 128; o += 4) {
        float a0 = bb[o], a1 = bb[o + 1], a2 = bb[o + 2], a3 = bb[o + 3];
#pragma unroll
        for (int cc = 0; cc < 64; ++cc) {
            float4 wv = *(const float4*)&w2[cc][o];
            float x = xa[cc];
            a0 += x * wv.x; a1 += x * wv.y; a2 += x * wv.z; a3 += x * wv.w;
        }
        float4 sv = *(const float4*)&shp[o];
        float r0 = a0 + (sv.x * scs[o] + shs[o]);
        float r1 = a1 + (sv.y * scs[o + 1] + shs[o + 1]);
        float r2 = a2 + (sv.z * scs[o + 2] + shs[o + 2]);
        float r3 = a3 + (sv.w * scs[o + 3] + shs[o + 3]);
        out[((size_t)(b * C2 + o + 0)) * NN + n] = r0 >= 0.f ? r0 : 0.01f * r0;
        out[((size_t)(b * C2 + o + 1)) * NN + n] = r1 >= 0.f ? r1 : 0.01f * r1;
        out[((size_t)(b * C2 + o + 2)) * NN + n] = r2 >= 0.f ? r2 : 0.01f * r2;
        out[((size_t)(b * C2 + o + 3)) * NN + n] = r3 >= 0.f ? r3 : 0.01f * r3;
    }
}

extern "C" void kernel_launch(void* const* d_in, const int* in_sizes, int n_in,
                              void* d_out, int out_size, void* d_ws, size_t ws_size,
                              hipStream_t stream) {
    const float* coords    = (const float*)d_in[0];
    const float* features  = (const float*)d_in[1];
    const float* W_mlp1    = (const float*)d_in[2];
    const float* b_mlp1    = (const float*)d_in[3];
    const float* W_lse1    = (const float*)d_in[4];
    const float* b_lse1    = (const float*)d_in[5];
    const float* g_lse1    = (const float*)d_in[6];
    const float* be_lse1   = (const float*)d_in[7];
    const float* W_att1_lin= (const float*)d_in[8];
    const float* W_att1_mlp= (const float*)d_in[9];
    const float* b_att1_mlp= (const float*)d_in[10];
    const float* g_att1    = (const float*)d_in[11];
    const float* be_att1   = (const float*)d_in[12];
    const float* W_lse2    = (const float*)d_in[13];
    const float* b_lse2    = (const float*)d_in[14];
    const float* g_lse2    = (const float*)d_in[15];
    const float* be_lse2   = (const float*)d_in[16];
    const float* W_att2_lin= (const float*)d_in[17];
    const float* W_att2_mlp= (const float*)d_in[18];
    const float* b_att2_mlp= (const float*)d_in[19];
    const float* g_att2    = (const float*)d_in[20];
    const float* be_att2   = (const float*)d_in[21];
    const float* W_mlp2    = (const float*)d_in[22];
    const float* b_mlp2    = (const float*)d_in[23];
    const float* W_short   = (const float*)d_in[24];
    const float* b_short   = (const float*)d_in[25];
    const float* g_short   = (const float*)d_in[26];
    const float* be_short  = (const float*)d_in[27];

    float* ws = (float*)d_ws;
    float4* cp4      = (float4*)(ws + OFF_CP4);
    float* se        = ws + OFF_SE;
    float* xf        = ws + OFF_XF;
    float* short_pre = ws + OFF_SHORT;
    float* pre1      = ws + OFF_PRE1;
    float* pre2      = ws + OFF_PRE2;
    float* ss        = ws + OFF_SS;
    double* stats    = (double*)(ws + OFF_STATS);
    float* out       = (float*)d_out;

    hipMemsetAsync(stats, 0, S_TOTAL * sizeof(double), stream);

    k_prep<<<BNTOT / 256, 256, 0, stream>>>(coords, cp4);
    k_knn<<<256, 256, 0, stream>>>(cp4, se);
    k_feat<<<128, 128, 0, stream>>>(features, W_mlp1, b_mlp1, W_short, b_short,
                                    xf, short_pre, stats);
    k_lse_stats<<<256, 256, 0, stream>>>(se, W_lse1, b_lse1, W_lse2, b_lse2, stats);
    k_fin_misc<<<1, 192, 0, stream>>>(stats, ss, g_lse1, be_lse1, g_lse2, be_lse2,
                                      g_short, be_short);
    k_att<32, false><<<256, 256, 0, stream>>>(se, xf, W_lse1, b_lse1, W_att1_lin,
                                              W_att1_mlp, b_att1_mlp, ss,
                                              SS_LSE1, 0, S_ATT1, pre1, stats);
    k_fin_att<<<1, 64, 0, stream>>>(stats, ss, g_att1, be_att1, S_ATT1, 32, SS_ATT1);
    k_att<64, true><<<256, 256, 0, stream>>>(se, pre1, W_lse2, b_lse2, W_att2_lin,
                                             W_att2_mlp, b_att2_mlp, ss,
                                             SS_LSE2, SS_ATT1, S_ATT2, pre2, stats);
    k_fin_att<<<1, 64, 0, stream>>>(stats, ss, g_att2, be_att2, S_ATT2, 64, SS_ATT2);
    k_out<<<BNTOT / 256, 256, 0, stream>>>(pre2, short_pre, W_mlp2, b_mlp2, ss, out);
}

// Round 2
// 524.272 us; speedup vs baseline: 3.6738x; 3.6738x over previous
//
#include <hip/hip_runtime.h>
#include <cfloat>
#include <cmath>

#define DEV __device__ __forceinline__

constexpr int BB = 2, NN = 8192, KK = 16, CIN = 32, HH = 32, CO = 64, C2 = 128;
constexpr int BNTOT = BB * NN;        // 16384
constexpr int BNKROWS = BB * NN * KK; // 262144
constexpr float EPSF = 1e-6f;

// stats indices (doubles): [sum.., sumsq..] per group
constexpr int S_LSE1 = 0, S_LSE2 = 64, S_ATT1 = 128, S_ATT2 = 192, S_SHORT = 320, S_TOTAL = 576;
// scale/shift indices (floats): [scale.., shift..] per group
constexpr int SS_LSE1 = 0, SS_LSE2 = 64, SS_ATT1 = 128, SS_ATT2 = 192, SS_SHORT = 320, SS_TOTAL = 576;

// workspace layout (in floats)
constexpr size_t OFF_CP4   = 0;                                  // (x,y,z,sq) per point: 16384*4
constexpr size_t OFF_SE    = OFF_CP4 + (size_t)BNTOT * 4;        // se (B,N,K,10)
constexpr size_t OFF_XF    = OFF_SE + (size_t)BNKROWS * 10;      // mlp1 out (B,N,32)
constexpr size_t OFF_SHORT = OFF_XF + (size_t)BNTOT * HH;        // shortcut pre-BN (B,N,128)
constexpr size_t OFF_PRE1  = OFF_SHORT + (size_t)BNTOT * C2;     // att1 pre-BN (B,N,32)
constexpr size_t OFF_PRE2  = OFF_PRE1 + (size_t)BNTOT * HH;      // att2 pre-BN (B,N,64)
constexpr size_t OFF_SS    = OFF_PRE2 + (size_t)BNTOT * CO;      // scale/shift f32 x576
constexpr size_t OFF_STATS = OFF_SS + SS_TOTAL;                  // doubles x576

// ---------------- K0: pack (x,y,z,sq) ----------------
__global__ __launch_bounds__(256) void k_prep(const float* __restrict__ coords,
                                              float4* __restrict__ cp4) {
#pragma clang fp contract(off)
    int i = blockIdx.x * 256 + threadIdx.x;
    if (i >= BNTOT) return;
    float x = coords[3 * i], y = coords[3 * i + 1], z = coords[3 * i + 2];
    float sq = (x * x + y * y) + z * z;   // match numpy sum order, no FMA
    cp4[i] = make_float4(x, y, z, sq);
}

DEV float dist2(float4 qc, float4 c) {
#pragma clang fp contract(off)
    float dot = (qc.x * c.x + qc.y * c.y) + qc.z * c.z;
    return (qc.w + c.w) - 2.0f * dot;   // exact jax/np expansion formula
}

// strict-< sorted insert (stable for ascending-index insertion order)
DEV void ins16(float (&dl)[16], int (&il)[16], float d, int id) {
    float dk = d; int jk = id;
#pragma unroll
    for (int r = 0; r < 16; ++r) {
        bool c = dk < dl[r];
        float td = dl[r]; int ti = il[r];
        dl[r] = c ? dk : dl[r]; il[r] = c ? jk : il[r];
        dk = c ? td : dk; jk = c ? ti : jk;
    }
}

// lexicographic (d, idx) insert — used when merging lists from different index ranges
DEV void ins16_lex(float (&dl)[16], int (&il)[16], float d, int id) {
    float dk = d; int jk = id;
#pragma unroll
    for (int r = 0; r < 16; ++r) {
        bool c = (dk < dl[r]) || (dk == dl[r] && jk < il[r]);
        float td = dl[r]; int ti = il[r];
        dl[r] = c ? dk : dl[r]; il[r] = c ? jk : il[r];
        dk = c ? td : dk; jk = c ? ti : jk;
    }
}

// ---------------- K1: fused KNN + spatial encoding ----------------
// grid: 512 blocks = 2 batches x 256 query-groups of 32.
// block: 256 threads; thread t: query = t&31, partition = t>>5 (8 x 1024 candidates).
// Candidates read straight from L2 (cp4 = 128KB/batch, fully cached; 32 lanes share
// each address -> broadcast). Per-lane buffered inserts amortize the wave-divergent
// sorted-insert chain: append (d2,idx) to LDS when below (stale) threshold; run the
// chain only when some lane has >=4 buffered.
__global__ __launch_bounds__(256) void k_knn(const float4* __restrict__ cp4,
                                             float* __restrict__ se) {
    __shared__ uint2 buf[7][256];          // 14 KB append buffer [slot][tid]
    __shared__ float mdl[8][32][17];       // published lists (pad 17 vs bank conflicts)
    __shared__ int   mil[8][32][17];

    int t = threadIdx.x;
    int b = blockIdx.x >> 8;
    int qbase = (blockIdx.x & 255) * 32;
    int ql = t & 31, part = t >> 5;
    const float4* cp = cp4 + (size_t)b * NN;
    float4 qc = cp[qbase + ql];

    float dl[16]; int il[16];
#pragma unroll
    for (int i = 0; i < 16; ++i) { dl[i] = FLT_MAX; il[i] = 0; }

    int cb = part * 1024;
    // seed: first 16 candidates of the partition (unconditional inserts)
#pragma unroll
    for (int k = 0; k < 16; ++k) ins16(dl, il, dist2(qc, cp[cb + k]), cb + k);
    float worst = dl[15];
    int cnt = 0;

    for (int j = cb + 16; j < cb + 1024; j += 4) {
        float4 c0 = cp[j], c1 = cp[j + 1], c2 = cp[j + 2], c3 = cp[j + 3];
        float d0 = dist2(qc, c0), d1 = dist2(qc, c1), d2v = dist2(qc, c2), d3 = dist2(qc, c3);
        bool p0 = d0 < worst, p1 = d1 < worst, p2 = d2v < worst, p3 = d3 < worst;
        if (__any(p0 | p1 | p2 | p3)) {
            if (p0) { buf[cnt][t] = make_uint2(__float_as_uint(d0), (unsigned)(j)); ++cnt; }
            if (p1) { buf[cnt][t] = make_uint2(__float_as_uint(d1), (unsigned)(j + 1)); ++cnt; }
            if (p2) { buf[cnt][t] = make_uint2(__float_as_uint(d2v), (unsigned)(j + 2)); ++cnt; }
            if (p3) { buf[cnt][t] = make_uint2(__float_as_uint(d3), (unsigned)(j + 3)); ++cnt; }
            if (__any(cnt >= 4)) {
#pragma unroll
                for (int s = 0; s < 7; ++s) {
                    if (s < cnt) {
                        uint2 v = buf[s][t];
                        float d = __uint_as_float(v.x);
                        if (d < dl[15]) ins16(dl, il, d, (int)v.y);
                    }
                }
                cnt = 0;
                worst = dl[15];
            }
        }
    }
    if (__any(cnt > 0)) {   // final flush
#pragma unroll
        for (int s = 0; s < 7; ++s) {
            if (s < cnt) {
                uint2 v = buf[s][t];
                float d = __uint_as_float(v.x);
                if (d < dl[15]) ins16(dl, il, d, (int)v.y);
            }
        }
    }

    // publish all partial lists
#pragma unroll
    for (int i = 0; i < 16; ++i) { mdl[part][ql][i] = dl[i]; mil[part][ql][i] = il[i]; }
    __syncthreads();

    // pairwise merge tree: 8 -> 4 -> 2 -> 1 (lex compare for cross-partition stability)
    for (int half = 4; half >= 1; half >>= 1) {
        if (part < half) {
#pragma unroll
            for (int i = 0; i < 16; ++i) {
                float d = mdl[part + half][ql][i]; int id = mil[part + half][ql][i];
                if (d < dl[15] || (d == dl[15] && id < il[15])) ins16_lex(dl, il, d, id);
            }
#pragma unroll
            for (int i = 0; i < 16; ++i) { mdl[part][ql][i] = dl[i]; mil[part][ql][i] = il[i]; }
        }
        __syncthreads();
    }

    // epilogue: all 256 threads write se rows (2 (q,k) slots each)
    for (int s = t; s < 512; s += 256) {
        int qq = s >> 4, k = s & 15;
        float d2s = mdl[0][qq][k]; int id = mil[0][qq][k];
        float4 qc2 = cp[qbase + qq];
        float4 nb = cp[id];
        float dist = sqrtf(fmaxf(d2s, 1e-12f));
        float* sp = se + ((size_t)(b * NN + qbase + qq) * KK + k) * 10;
        sp[0] = qc2.x; sp[1] = qc2.y; sp[2] = qc2.z;
        sp[3] = nb.x;  sp[4] = nb.y;  sp[5] = nb.z;
        sp[6] = qc2.x - nb.x; sp[7] = qc2.y - nb.y; sp[8] = qc2.z - nb.z;
        sp[9] = dist;
    }
}

// ---------------- K2: mlp1 + shortcut linear + shortcut BN stats ----------------
// block: 128 threads (thread = output channel), 64 points; grid: 256 blocks.
__global__ __launch_bounds__(128) void k_feat(const float* __restrict__ feat,
                                              const float* __restrict__ Wm1, const float* __restrict__ bm1,
                                              const float* __restrict__ Wsh, const float* __restrict__ bsh,
                                              float* __restrict__ xf, float* __restrict__ short_pre,
                                              double* __restrict__ stats) {
    __shared__ float fl[32][33];
    int t = threadIdx.x;
    int pbase = blockIdx.x * 64;
    float wcol[32];
#pragma unroll
    for (int i = 0; i < 32; ++i) wcol[i] = Wsh[i * C2 + t];
    float wm[32];
    if (t < 32) {
#pragma unroll
        for (int i = 0; i < 32; ++i) wm[i] = Wm1[i * HH + t];
    }
    float bs = bsh[t];
    float bm = (t < 32) ? bm1[t] : 0.f;
    double s = 0.0, s2 = 0.0;

    for (int c0 = 0; c0 < 64; c0 += 32) {
        __syncthreads();
        for (int e = t; e < 1024; e += 128) {
            int p = e >> 5, i = e & 31;
            fl[p][i] = feat[(size_t)(pbase + c0 + p) * CIN + i];
        }
        __syncthreads();
        for (int p = 0; p < 32; ++p) {
            float acc = bs;
#pragma unroll
            for (int i = 0; i < 32; ++i) acc += fl[p][i] * wcol[i];
            int gp = pbase + c0 + p;
            short_pre[(size_t)gp * C2 + t] = acc;
            s += acc; s2 += (double)acc * acc;
            if (t < 32) {
                float xv = bm;
#pragma unroll
                for (int i = 0; i < 32; ++i) xv += fl[p][i] * wm[i];
                xf[(size_t)gp * HH + t] = xv >= 0.f ? xv : 0.2f * xv;
            }
        }
    }
    atomicAdd(&stats[S_SHORT + t], s);
    atomicAdd(&stats[S_SHORT + C2 + t], s2);
}

// ---------------- K3: lse1+lse2 linear BN stats ----------------
__global__ __launch_bounds__(256) void k_lse_stats(const float* __restrict__ se,
                                                   const float* __restrict__ W1, const float* __restrict__ b1,
                                                   const float* __restrict__ W2, const float* __restrict__ b2,
                                                   double* __restrict__ stats) {
    int t = threadIdx.x;
    int c = t & 63, grp = t >> 6;
    int ch = c & 31; bool second = c >= 32;
    const float* W = second ? W2 : W1;
    float wcol[10];
#pragma unroll
    for (int d = 0; d < 10; ++d) wcol[d] = W[d * HH + ch];
    float bb = second ? b2[ch] : b1[ch];
    double s = 0.0, s2 = 0.0;
    int rbase = blockIdx.x * 1024;
    for (int r = grp; r < 1024; r += 4) {
        const float* sr = se + (size_t)(rbase + r) * 10;
        float acc = bb;
#pragma unroll
        for (int d = 0; d < 10; ++d) acc += sr[d] * wcol[d];
        s += acc; s2 += (double)acc * acc;
    }
    __shared__ double red[4][64][2];
    red[grp][c][0] = s; red[grp][c][1] = s2;
    __syncthreads();
    if (grp == 0) {
        for (int g = 1; g < 4; ++g) { s += red[g][c][0]; s2 += red[g][c][1]; }
        int base = second ? S_LSE2 : S_LSE1;
        atomicAdd(&stats[base + ch], s);
        atomicAdd(&stats[base + 32 + ch], s2);
    }
}

// ---------------- BN finalize helpers ----------------
DEV void fin_one(const double* stats, int sbase, int ch, int nch, double M,
                 const float* g, const float* be, float* ss, int ssbase) {
    double mean = stats[sbase + ch] / M;
    double var = stats[sbase + nch + ch] / M - mean * mean;
    double scale = (double)g[ch] / sqrt(var + (double)EPSF);
    double shift = (double)be[ch] - mean * scale;
    ss[ssbase + ch] = (float)scale;
    ss[ssbase + nch + ch] = (float)shift;
}

__global__ void k_fin_misc(const double* __restrict__ stats, float* __restrict__ ss,
                           const float* g1, const float* be1, const float* g2, const float* be2,
                           const float* gs, const float* bes) {
    int t = threadIdx.x;
    if (t < 32) fin_one(stats, S_LSE1, t, 32, (double)BNKROWS, g1, be1, ss, SS_LSE1);
    else if (t < 64) fin_one(stats, S_LSE2, t - 32, 32, (double)BNKROWS, g2, be2, ss, SS_LSE2);
    else if (t < 192) fin_one(stats, S_SHORT, t - 64, 128, (double)BNTOT, gs, bes, ss, SS_SHORT);
}

__global__ void k_fin_att(const double* __restrict__ stats, float* __restrict__ ss,
                          const float* g, const float* be, int sbase, int nch, int ssbase) {
    int t = threadIdx.x;
    if (t < nch) fin_one(stats, sbase, t, nch, (double)BNTOT, g, be, ss, ssbase);
}

// ---------------- K5/K7: fused LocSE + attentive pooling + MLP ----------------
// grid 512 x 256 (4 waves); wave handles 8 points; lane = x1 channel (0..63).
template <int OUTC, bool SECOND>
__global__ __launch_bounds__(256) void k_att(const float* __restrict__ se,
                                             const float* __restrict__ featsrc,
                                             const float* __restrict__ Wlse, const float* __restrict__ blse,
                                             const float* __restrict__ Wlin,
                                             const float* __restrict__ Wmlp, const float* __restrict__ bmlp,
                                             const float* __restrict__ ss, int lse_ss, int feat_ss, int stat_base,
                                             float* __restrict__ preout, double* __restrict__ stats) {
    __shared__ __align__(16) float wlt[64][68];   // W_att_lin transposed, padded
    __shared__ float wm[64][OUTC];
    __shared__ __align__(16) float x1[4][16][64];
    __shared__ float p1b[4][64];
    __shared__ double red[4][OUTC][2];

    int t = threadIdx.x, w = t >> 6, c = t & 63;
    for (int e = t; e < 4096; e += 256) wlt[e & 63][e >> 6] = Wlin[e];
    for (int e = t; e < 64 * OUTC; e += 256) wm[e / OUTC][e % OUTC] = Wmlp[e];

    float wf[10]; float bf = 0.f;
    if (c < 32) {   // fold BN scale/shift into LocSE weights
        float sc_ = ss[lse_ss + c], sh_ = ss[lse_ss + 32 + c];
#pragma unroll
        for (int d = 0; d < 10; ++d) wf[d] = Wlse[d * 32 + c] * sc_;
        bf = blse[c] * sc_ + sh_;
    }
    float fa = 1.f, fb = 0.f;
    if (SECOND && c >= 32) { fa = ss[feat_ss + (c - 32)]; fb = ss[feat_ss + 32 + (c - 32)]; }
    double s = 0.0, s2 = 0.0;
    __syncthreads();

    for (int i = 0; i < 8; ++i) {
        int p = blockIdx.x * 32 + w * 8 + i;
        float col[16];
        if (c < 32) {
            const float* sp = se + (size_t)p * (KK * 10);
#pragma unroll
            for (int k = 0; k < 16; ++k) {
                float acc = bf;
#pragma unroll
                for (int d = 0; d < 10; ++d) acc += sp[k * 10 + d] * wf[d];
                col[k] = fmaxf(acc, 0.f);
            }
        } else {
            float xv = featsrc[(size_t)p * 32 + (c - 32)];
            if (SECOND) xv = fmaxf(xv * fa + fb, 0.f);
#pragma unroll
            for (int k = 0; k < 16; ++k) col[k] = xv;
        }
#pragma unroll
        for (int k = 0; k < 16; ++k) x1[w][k][c] = col[k];

        float scv[16];
#pragma unroll
        for (int k = 0; k < 16; ++k) scv[k] = 0.f;
        for (int dg = 0; dg < 16; ++dg) {
            float4 wv = *(const float4*)&wlt[c][dg * 4];
#pragma unroll
            for (int k = 0; k < 16; ++k) {
                float4 xv = *(const float4*)&x1[w][k][dg * 4];
                scv[k] += xv.x * wv.x + xv.y * wv.y + xv.z * wv.z + xv.w * wv.w;
            }
        }
        float m = scv[0];
#pragma unroll
        for (int k = 1; k < 16; ++k) m = fmaxf(m, scv[k]);
        float sum = 0.f, p1 = 0.f;
#pragma unroll
        for (int k = 0; k < 16; ++k) { float e = __expf(scv[k] - m); sum += e; p1 += e * col[k]; }
        p1 /= sum;
        p1b[w][c] = p1;

        if (c < OUTC) {
            float acc = bmlp[c];
#pragma unroll
            for (int d = 0; d < 64; ++d) acc += p1b[w][d] * wm[d][c];
            preout[(size_t)p * OUTC + c] = acc;
            s += acc; s2 += (double)acc * acc;
        }
    }
    if (c < OUTC) { red[w][c][0] = s; red[w][c][1] = s2; }
    __syncthreads();
    if (t < OUTC) {
        double ts = red[0][t][0], ts2 = red[0][t][1];
        for (int g = 1; g < 4; ++g) { ts += red[g][t][0]; ts2 += red[g][t][1]; }
        atomicAdd(&stats[stat_base + t], ts);
        atomicAdd(&stats[stat_base + OUTC + t], ts2);
    }
}

// ---------------- K9: final mlp2 + shortcut BN + residual leaky + transposed write ----
// grid 256 x 256; lane = point (64/block), wave seg = 32-output-channel slice.
__global__ __launch_bounds__(256) void k_out(const float* __restrict__ pre2,
                                             const float* __restrict__ short_pre,
                                             const float* __restrict__ W2, const float* __restrict__ b2,
                                             const float* __restrict__ ss, float* __restrict__ out) {
    __shared__ __align__(16) float w2[64][128];
    __shared__ float sc2[64], sh2[64], scs[128], shs[128], bb[128];
    int t = threadIdx.x;
    int pl = t & 63, seg = t >> 6;
    for (int e = t; e < 8192; e += 256) w2[e >> 7][e & 127] = W2[e];
    if (t < 64) { sc2[t] = ss[SS_ATT2 + t]; sh2[t] = ss[SS_ATT2 + 64 + t]; }
    if (t < 128) { scs[t] = ss[SS_SHORT + t]; shs[t] = ss[SS_SHORT + 128 + t]; bb[t] = b2[t]; }
    __syncthreads();

    int p = blockIdx.x * 64 + pl;
    int b = p >> 13, n = p & 8191;
    const float* pr = pre2 + (size_t)p * 64;
    float xa[64];
#pragma unroll
    for (int c = 0; c < 64; c += 4) {
        float4 v = *(const float4*)&pr[c];
        xa[c + 0] = fmaxf(v.x * sc2[c + 0] + sh2[c + 0], 0.f);
        xa[c + 1] = fmaxf(v.y * sc2[c + 1] + sh2[c + 1], 0.f);
        xa[c + 2] = fmaxf(v.z * sc2[c + 2] + sh2[c + 2], 0.f);
        xa[c + 3] = fmaxf(v.w * sc2[c + 3] + sh2[c + 3], 0.f);
    }
    const float* shp = short_pre + (size_t)p * 128;
    int obase = seg * 32;
    for (int o = obase; o < obase + 32; o += 4) {
        float a0 = bb[o], a1 = bb[o + 1], a2 = bb[o + 2], a3 = bb[o + 3];
#pragma unroll
        for (int cc = 0; cc < 64; ++cc) {
            float4 wv = *(const float4*)&w2[cc][o];
            float x = xa[cc];
            a0 += x * wv.x; a1 += x * wv.y; a2 += x * wv.z; a3 += x * wv.w;
        }
        float4 sv = *(const float4*)&shp[o];
        float r0 = a0 + (sv.x * scs[o] + shs[o]);
        float r1 = a1 + (sv.y * scs[o + 1] + shs[o + 1]);
        float r2 = a2 + (sv.z * scs[o + 2] + shs[o + 2]);
        float r3 = a3 + (sv.w * scs[o + 3] + shs[o + 3]);
        out[((size_t)(b * C2 + o + 0)) * NN + n] = r0 >= 0.f ? r0 : 0.01f * r0;
        out[((size_t)(b * C2 + o + 1)) * NN + n] = r1 >= 0.f ? r1 : 0.01f * r1;
        out[((size_t)(b * C2 + o + 2)) * NN + n] = r2 >= 0.f ? r2 : 0.01f * r2;
        out[((size_t)(b * C2 + o + 3)) * NN + n] = r3 >= 0.f ? r3 : 0.01f * r3;
    }
}

extern "C" void kernel_launch(void* const* d_in, const int* in_sizes, int n_in,
                              void* d_out, int out_size, void* d_ws, size_t ws_size,
                              hipStream_t stream) {
    const float* coords    = (const float*)d_in[0];
    const float* features  = (const float*)d_in[1];
    const float* W_mlp1    = (const float*)d_in[2];
    const float* b_mlp1    = (const float*)d_in[3];
    const float* W_lse1    = (const float*)d_in[4];
    const float* b_lse1    = (const float*)d_in[5];
    const float* g_lse1    = (const float*)d_in[6];
    const float* be_lse1   = (const float*)d_in[7];
    const float* W_att1_lin= (const float*)d_in[8];
    const float* W_att1_mlp= (const float*)d_in[9];
    const float* b_att1_mlp= (const float*)d_in[10];
    const float* g_att1    = (const float*)d_in[11];
    const float* be_att1   = (const float*)d_in[12];
    const float* W_lse2    = (const float*)d_in[13];
    const float* b_lse2    = (const float*)d_in[14];
    const float* g_lse2    = (const float*)d_in[15];
    const float* be_lse2   = (const float*)d_in[16];
    const float* W_att2_lin= (const float*)d_in[17];
    const float* W_att2_mlp= (const float*)d_in[18];
    const float* b_att2_mlp= (const float*)d_in[19];
    const float* g_att2    = (const float*)d_in[20];
    const float* be_att2   = (const float*)d_in[21];
    const float* W_mlp2    = (const float*)d_in[22];
    const float* b_mlp2    = (const float*)d_in[23];
    const float* W_short   = (const float*)d_in[24];
    const float* b_short   = (const float*)d_in[25];
    const float* g_short   = (const float*)d_in[26];
    const float* be_short  = (const float*)d_in[27];

    float* ws = (float*)d_ws;
    float4* cp4      = (float4*)(ws + OFF_CP4);
    float* se        = ws + OFF_SE;
    float* xf        = ws + OFF_XF;
    float* short_pre = ws + OFF_SHORT;
    float* pre1      = ws + OFF_PRE1;
    float* pre2      = ws + OFF_PRE2;
    float* ss        = ws + OFF_SS;
    double* stats    = (double*)(ws + OFF_STATS);
    float* out       = (float*)d_out;

    hipMemsetAsync(stats, 0, S_TOTAL * sizeof(double), stream);

    k_prep<<<BNTOT / 256, 256, 0, stream>>>(coords, cp4);
    k_knn<<<512, 256, 0, stream>>>(cp4, se);
    k_feat<<<256, 128, 0, stream>>>(features, W_mlp1, b_mlp1, W_short, b_short,
                                    xf, short_pre, stats);
    k_lse_stats<<<256, 256, 0, stream>>>(se, W_lse1, b_lse1, W_lse2, b_lse2, stats);
    k_fin_misc<<<1, 192, 0, stream>>>(stats, ss, g_lse1, be_lse1, g_lse2, be_lse2,
                                      g_short, be_short);
    k_att<32, false><<<512, 256, 0, stream>>>(se, xf, W_lse1, b_lse1, W_att1_lin,
                                              W_att1_mlp, b_att1_mlp, ss,
                                              SS_LSE1, 0, S_ATT1, pre1, stats);
    k_fin_att<<<1, 64, 0, stream>>>(stats, ss, g_att1, be_att1, S_ATT1, 32, SS_ATT1);
    k_att<64, true><<<512, 256, 0, stream>>>(se, pre1, W_lse2, b_lse2, W_att2_lin,
                                             W_att2_mlp, b_att2_mlp, ss,
                                             SS_LSE2, SS_ATT1, S_ATT2, pre2, stats);
    k_fin_att<<<1, 64, 0, stream>>>(stats, ss, g_att2, be_att2, S_ATT2, 64, SS_ATT2);
    k_out<<<BNTOT / 64, 256, 0, stream>>>(pre2, short_pre, W_mlp2, b_mlp2, ss, out);
}

// Round 3
// 406.856 us; speedup vs baseline: 4.7341x; 1.2886x over previous
//
#include <hip/hip_runtime.h>
#include <cfloat>
#include <cmath>

#define DEV __device__ __forceinline__

constexpr int BB = 2, NN = 8192, KK = 16, CIN = 32, HH = 32, CO = 64, C2 = 128;
constexpr int BNTOT = BB * NN;        // 16384
constexpr int BNKROWS = BB * NN * KK; // 262144
constexpr float EPSF = 1e-6f;

// stats indices (doubles): [sum.., sumsq..] per group
constexpr int S_LSE1 = 0, S_LSE2 = 64, S_ATT1 = 128, S_ATT2 = 192, S_SHORT = 320, S_TOTAL = 576;
// scale/shift indices (floats): [scale.., shift..] per group
constexpr int SS_LSE1 = 0, SS_LSE2 = 64, SS_ATT1 = 128, SS_ATT2 = 192, SS_SHORT = 320, SS_TOTAL = 576;

// workspace layout (in floats)
constexpr size_t OFF_CP4   = 0;
constexpr size_t OFF_SE    = OFF_CP4 + (size_t)BNTOT * 4;
constexpr size_t OFF_XF    = OFF_SE + (size_t)BNKROWS * 10;
constexpr size_t OFF_SHORT = OFF_XF + (size_t)BNTOT * HH;
constexpr size_t OFF_PRE1  = OFF_SHORT + (size_t)BNTOT * C2;
constexpr size_t OFF_PRE2  = OFF_PRE1 + (size_t)BNTOT * HH;
constexpr size_t OFF_SS    = OFF_PRE2 + (size_t)BNTOT * CO;
constexpr size_t OFF_STATS = OFF_SS + SS_TOTAL;

// ---------------- K0: pack (x,y,z,sq) ----------------
__global__ __launch_bounds__(256) void k_prep(const float* __restrict__ coords,
                                              float4* __restrict__ cp4) {
#pragma clang fp contract(off)
    int i = blockIdx.x * 256 + threadIdx.x;
    if (i >= BNTOT) return;
    float x = coords[3 * i], y = coords[3 * i + 1], z = coords[3 * i + 2];
    float sq = (x * x + y * y) + z * z;   // match numpy sum order, no FMA
    cp4[i] = make_float4(x, y, z, sq);
}

DEV float dist2(float4 qc, float4 c) {
#pragma clang fp contract(off)
    float dot = (qc.x * c.x + qc.y * c.y) + qc.z * c.z;
    return (qc.w + c.w) - 2.0f * dot;   // exact jax/np expansion formula
}

// order-preserving float->uint encoding (monotone for all finite floats)
DEV unsigned encf(float f) {
    unsigned u = __float_as_uint(f);
    return (u & 0x80000000u) ? ~u : (u | 0x80000000u);
}
DEV float decf(unsigned e) {
    unsigned u = (e & 0x80000000u) ? (e & 0x7FFFFFFFu) : ~e;
    return __uint_as_float(u);
}

// strict-< sorted insert (stable == lex for ascending-index insertion order)
DEV void ins16(float (&dl)[16], int (&il)[16], float d, int id) {
    float dk = d; int jk = id;
#pragma unroll
    for (int r = 0; r < 16; ++r) {
        bool c = dk < dl[r];
        float td = dl[r]; int ti = il[r];
        dl[r] = c ? dk : dl[r]; il[r] = c ? jk : il[r];
        dk = c ? td : dk; jk = c ? ti : jk;
    }
}

// lexicographic (d, idx) insert — for merging lists from different index ranges
DEV void ins16_lex(float (&dl)[16], int (&il)[16], float d, int id) {
    float dk = d; int jk = id;
#pragma unroll
    for (int r = 0; r < 16; ++r) {
        bool c = (dk < dl[r]) || (dk == dl[r] && jk < il[r]);
        float td = dl[r]; int ti = il[r];
        dl[r] = c ? dk : dl[r]; il[r] = c ? jk : il[r];
        dk = c ? td : dk; jk = c ? ti : jk;
    }
}

// ---------------- K1: fused KNN + spatial encoding ----------------
// grid 512 = 2 batches x 256 query-groups of 32; block 256; thread: query=t&31,
// partition=t>>5 (8 x 1024 candidates). Shared per-query union threshold T
// (min over published per-thread 16th-bests, LDS atomicMin on ordered uint):
// any candidate with d > T cannot be in the union top-16, so per-thread accept
// work drops from ~66 to ~12 per scan. Stale T is larger -> conservative -> safe.
__global__ __launch_bounds__(256) void k_knn(const float4* __restrict__ cp4,
                                             float* __restrict__ se) {
    __shared__ uint2 buf[7][256];          // append buffer [slot][tid]
    __shared__ float mdl[8][32][17];
    __shared__ int   mil[8][32][17];
    __shared__ unsigned thr[32];           // per-query union threshold (encoded)

    int t = threadIdx.x;
    int b = blockIdx.x >> 8;
    int qbase = (blockIdx.x & 255) * 32;
    int ql = t & 31, part = t >> 5;
    const float4* cp = cp4 + (size_t)b * NN;
    float4 qc = cp[qbase + ql];

    if (t < 32) thr[t] = encf(FLT_MAX);
    __syncthreads();

    float dl[16]; int il[16];
#pragma unroll
    for (int i = 0; i < 16; ++i) { dl[i] = FLT_MAX; il[i] = 0; }

    int cb = part * 1024;
    // seed: first 16 candidates of the partition (unconditional)
#pragma unroll
    for (int k = 0; k < 16; ++k) ins16(dl, il, dist2(qc, cp[cb + k]), cb + k);
    atomicMin(&thr[ql], encf(dl[15]));
    float Tf = dl[15];
    int cnt = 0;

    // prefetch pipeline: candidates one iteration ahead; threshold one iter stale
    float4 n0 = cp[cb + 16], n1 = cp[cb + 17], n2 = cp[cb + 18], n3 = cp[cb + 19];
    unsigned te = thr[ql];
    for (int j = cb + 16; j < cb + 1024; j += 4) {
        float4 c0 = n0, c1 = n1, c2 = n2, c3 = n3;
        n0 = cp[j + 4]; n1 = cp[j + 5]; n2 = cp[j + 6]; n3 = cp[j + 7]; // 64B over-read at end: lands in se region of ws, unused
        float d0 = dist2(qc, c0), d1 = dist2(qc, c1), d2v = dist2(qc, c2), d3 = dist2(qc, c3);
        bool p0 = d0 <= Tf, p1 = d1 <= Tf, p2 = d2v <= Tf, p3 = d3 <= Tf;
        if (__any(p0 | p1 | p2 | p3)) {
            if (p0) { buf[cnt][t] = make_uint2(__float_as_uint(d0), (unsigned)(j)); ++cnt; }
            if (p1) { buf[cnt][t] = make_uint2(__float_as_uint(d1), (unsigned)(j + 1)); ++cnt; }
            if (p2) { buf[cnt][t] = make_uint2(__float_as_uint(d2v), (unsigned)(j + 2)); ++cnt; }
            if (p3) { buf[cnt][t] = make_uint2(__float_as_uint(d3), (unsigned)(j + 3)); ++cnt; }
            if (__any(cnt >= 4)) {
#pragma unroll
                for (int s = 0; s < 7; ++s) {
                    if (s < cnt) {
                        uint2 v = buf[s][t];
                        float d = __uint_as_float(v.x);
                        if (d < dl[15]) ins16(dl, il, d, (int)v.y);
                    }
                }
                cnt = 0;
                atomicMin(&thr[ql], encf(dl[15]));
            }
        }
        Tf = decf(te);        // adopt last iteration's published min
        te = thr[ql];         // issue refresh for next iteration (latency hidden)
    }
    if (__any(cnt > 0)) {
#pragma unroll
        for (int s = 0; s < 7; ++s) {
            if (s < cnt) {
                uint2 v = buf[s][t];
                float d = __uint_as_float(v.x);
                if (d < dl[15]) ins16(dl, il, d, (int)v.y);
            }
        }
    }

#pragma unroll
    for (int i = 0; i < 16; ++i) { mdl[part][ql][i] = dl[i]; mil[part][ql][i] = il[i]; }
    __syncthreads();

    // pairwise merge tree 8->4->2->1 (lex for cross-partition stability)
    for (int half = 4; half >= 1; half >>= 1) {
        if (part < half) {
#pragma unroll
            for (int i = 0; i < 16; ++i) {
                float d = mdl[part + half][ql][i]; int id = mil[part + half][ql][i];
                if (d < dl[15] || (d == dl[15] && id < il[15])) ins16_lex(dl, il, d, id);
            }
#pragma unroll
            for (int i = 0; i < 16; ++i) { mdl[part][ql][i] = dl[i]; mil[part][ql][i] = il[i]; }
        }
        __syncthreads();
    }

    // epilogue: all 256 threads write se rows (2 (q,k) slots each)
    for (int s = t; s < 512; s += 256) {
        int qq = s >> 4, k = s & 15;
        float d2s = mdl[0][qq][k]; int id = mil[0][qq][k];
        float4 qc2 = cp[qbase + qq];
        float4 nb = cp[id];
        float dist = sqrtf(fmaxf(d2s, 1e-12f));
        float* sp = se + ((size_t)(b * NN + qbase + qq) * KK + k) * 10;
        sp[0] = qc2.x; sp[1] = qc2.y; sp[2] = qc2.z;
        sp[3] = nb.x;  sp[4] = nb.y;  sp[5] = nb.z;
        sp[6] = qc2.x - nb.x; sp[7] = qc2.y - nb.y; sp[8] = qc2.z - nb.z;
        sp[9] = dist;
    }
}

// ---------------- K2: mlp1 + shortcut linear + shortcut BN stats ----------------
// grid 512 x 128 threads; 32 points per block.
__global__ __launch_bounds__(128) void k_feat(const float* __restrict__ feat,
                                              const float* __restrict__ Wm1, const float* __restrict__ bm1,
                                              const float* __restrict__ Wsh, const float* __restrict__ bsh,
                                              float* __restrict__ xf, float* __restrict__ short_pre,
                                              double* __restrict__ stats) {
    __shared__ float fl[32][33];
    int t = threadIdx.x;
    int pbase = blockIdx.x * 32;
    float wcol[32];
#pragma unroll
    for (int i = 0; i < 32; ++i) wcol[i] = Wsh[i * C2 + t];
    float wm[32];
    if (t < 32) {
#pragma unroll
        for (int i = 0; i < 32; ++i) wm[i] = Wm1[i * HH + t];
    }
    float bs = bsh[t];
    float bm = (t < 32) ? bm1[t] : 0.f;
    double s = 0.0, s2 = 0.0;

    for (int e = t; e < 1024; e += 128) {
        int p = e >> 5, i = e & 31;
        fl[p][i] = feat[(size_t)(pbase + p) * CIN + i];
    }
    __syncthreads();
    for (int p = 0; p < 32; ++p) {
        float acc = bs;
#pragma unroll
        for (int i = 0; i < 32; ++i) acc += fl[p][i] * wcol[i];
        int gp = pbase + p;
        short_pre[(size_t)gp * C2 + t] = acc;
        s += acc; s2 += (double)acc * acc;
        if (t < 32) {
            float xv = bm;
#pragma unroll
            for (int i = 0; i < 32; ++i) xv += fl[p][i] * wm[i];
            xf[(size_t)gp * HH + t] = xv >= 0.f ? xv : 0.2f * xv;
        }
    }
    atomicAdd(&stats[S_SHORT + t], s);
    atomicAdd(&stats[S_SHORT + C2 + t], s2);
}

// ---------------- K3: lse1+lse2 linear BN stats (LDS-staged, coalesced) ----------------
// grid 512 x 256; block processes 512 rows in two 256-row LDS tiles.
__global__ __launch_bounds__(256) void k_lse_stats(const float* __restrict__ se,
                                                   const float* __restrict__ W1, const float* __restrict__ b1,
                                                   const float* __restrict__ W2, const float* __restrict__ b2,
                                                   double* __restrict__ stats) {
    __shared__ float srows[256][10];
    __shared__ double red[4][64][2];
    int t = threadIdx.x;
    int c = t & 63, grp = t >> 6;
    int ch = c & 31; bool second = c >= 32;
    const float* W = second ? W2 : W1;
    float wcol[10];
#pragma unroll
    for (int d = 0; d < 10; ++d) wcol[d] = W[d * HH + ch];
    float bb = second ? b2[ch] : b1[ch];
    double s = 0.0, s2 = 0.0;
    int rbase = blockIdx.x * 512;

    for (int tile = 0; tile < 2; ++tile) {
        __syncthreads();
        const float* src = se + (size_t)(rbase + tile * 256) * 10;
        for (int e = t; e < 2560; e += 256) srows[e / 10][e % 10] = src[e];
        __syncthreads();
        int r0 = grp * 64;
        for (int r = r0; r < r0 + 64; ++r) {
            float acc = bb;
#pragma unroll
            for (int d = 0; d < 10; ++d) acc += srows[r][d] * wcol[d];
            s += acc; s2 += (double)acc * acc;
        }
    }
    red[grp][c][0] = s; red[grp][c][1] = s2;
    __syncthreads();
    if (grp == 0) {
        for (int g = 1; g < 4; ++g) { s += red[g][c][0]; s2 += red[g][c][1]; }
        int base = second ? S_LSE2 : S_LSE1;
        atomicAdd(&stats[base + ch], s);
        atomicAdd(&stats[base + 32 + ch], s2);
    }
}

// ---------------- BN finalize helpers ----------------
DEV void fin_one(const double* stats, int sbase, int ch, int nch, double M,
                 const float* g, const float* be, float* ss, int ssbase) {
    double mean = stats[sbase + ch] / M;
    double var = stats[sbase + nch + ch] / M - mean * mean;
    double scale = (double)g[ch] / sqrt(var + (double)EPSF);
    double shift = (double)be[ch] - mean * scale;
    ss[ssbase + ch] = (float)scale;
    ss[ssbase + nch + ch] = (float)shift;
}

__global__ void k_fin_misc(const double* __restrict__ stats, float* __restrict__ ss,
                           const float* g1, const float* be1, const float* g2, const float* be2,
                           const float* gs, const float* bes) {
    int t = threadIdx.x;
    if (t < 32) fin_one(stats, S_LSE1, t, 32, (double)BNKROWS, g1, be1, ss, SS_LSE1);
    else if (t < 64) fin_one(stats, S_LSE2, t - 32, 32, (double)BNKROWS, g2, be2, ss, SS_LSE2);
    else if (t < 192) fin_one(stats, S_SHORT, t - 64, 128, (double)BNTOT, gs, bes, ss, SS_SHORT);
}

__global__ void k_fin_att(const double* __restrict__ stats, float* __restrict__ ss,
                          const float* g, const float* be, int sbase, int nch, int ssbase) {
    int t = threadIdx.x;
    if (t < nch) fin_one(stats, sbase, t, nch, (double)BNTOT, g, be, ss, ssbase);
}

// ---------------- K5/K7: fused LocSE + attentive pooling + MLP ----------------
// grid 512 x 256 (4 waves); wave handles 8 points; lane l: channel c=l (x1 column).
// Algebraic cuts: (1) x1 cols >=32 are k-constant -> score = sum_{d<32} sp1*W + cst_c
// where cst_c uses the feature vector once; (2) LocSE split across lane halves
// (lane c<32 computes k=0..7 of ch c; lane c+32 computes k=8..15 of ch c).
template <int OUTC, bool SECOND>
__global__ __launch_bounds__(256) void k_att(const float* __restrict__ se,
                                             const float* __restrict__ featsrc,
                                             const float* __restrict__ Wlse, const float* __restrict__ blse,
                                             const float* __restrict__ Wlin,
                                             const float* __restrict__ Wmlp, const float* __restrict__ bmlp,
                                             const float* __restrict__ ss, int lse_ss, int feat_ss, int stat_base,
                                             float* __restrict__ preout, double* __restrict__ stats) {
    __shared__ __align__(16) float wlt[64][68];   // W_att_lin transposed (row = out channel c)
    __shared__ float wm[64][OUTC];
    __shared__ __align__(16) float x1[4][16][40]; // sp1 part only (cols 0..31), 160B rows
    __shared__ float fv[4][32];                   // per-wave feature vector (x1 cols 32..63)
    __shared__ float p1b[4][64];
    __shared__ double red[4][OUTC][2];

    int t = threadIdx.x, w = t >> 6, c = t & 63;
    int ch = c & 31, half = c >> 5;
    for (int e = t; e < 4096; e += 256) wlt[e & 63][e >> 6] = Wlin[e];
    for (int e = t; e < 64 * OUTC; e += 256) wm[e / OUTC][e % OUTC] = Wmlp[e];

    // folded LocSE weights for channel ch (all lanes)
    float wf[10]; float bf;
    {
        float sc_ = ss[lse_ss + ch], sh_ = ss[lse_ss + 32 + ch];
#pragma unroll
        for (int d = 0; d < 10; ++d) wf[d] = Wlse[d * 32 + ch] * sc_;
        bf = blse[ch] * sc_ + sh_;
    }
    float fa = 1.f, fb = 0.f;
    if (SECOND && c >= 32) { fa = ss[feat_ss + ch]; fb = ss[feat_ss + 32 + ch]; }
    double s = 0.0, s2 = 0.0;
    __syncthreads();

    for (int i = 0; i < 8; ++i) {
        int p = blockIdx.x * 32 + w * 8 + i;

        // LocSE: lane computes 8 k-rows for channel ch (half selects k-range)
        int kbase = half * 8;
        const float* sp = se + (size_t)p * (KK * 10) + kbase * 10;
        float myv[8];
#pragma unroll
        for (int kk = 0; kk < 8; ++kk) {
            float acc = bf;
#pragma unroll
            for (int d = 0; d < 10; ++d) acc += sp[kk * 10 + d] * wf[d];
            myv[kk] = fmaxf(acc, 0.f);
        }
#pragma unroll
        for (int kk = 0; kk < 8; ++kk) x1[w][kbase + kk][ch] = myv[kk];

        float xv = 0.f;
        if (c >= 32) {
            xv = featsrc[(size_t)p * 32 + ch];
            if (SECOND) xv = fmaxf(xv * fa + fb, 0.f);
            fv[w][ch] = xv;
        }

        // own x1 column (for the weighted pool)
        float col[16];
        if (c < 32) {
#pragma unroll
            for (int kk = 0; kk < 8; ++kk) col[kk] = myv[kk];
#pragma unroll
            for (int kk = 0; kk < 8; ++kk) col[8 + kk] = x1[w][8 + kk][ch];
        } else {
#pragma unroll
            for (int k = 0; k < 16; ++k) col[k] = xv;
        }

        // constant score part from feature half: cst = sum_{d>=32} fv[d-32]*W[d][c]
        float cst = 0.f;
#pragma unroll
        for (int dg = 8; dg < 16; ++dg) {
            float4 wv = *(const float4*)&wlt[c][dg * 4];
            float4 xvv = *(const float4*)&fv[w][(dg - 8) * 4];
            cst += xvv.x * wv.x + xvv.y * wv.y + xvv.z * wv.z + xvv.w * wv.w;
        }
        // scores over sp1 half (d<32)
        float scv[16];
#pragma unroll
        for (int k = 0; k < 16; ++k) scv[k] = cst;
        for (int dg = 0; dg < 8; ++dg) {
            float4 wv = *(const float4*)&wlt[c][dg * 4];
#pragma unroll
            for (int k = 0; k < 16; ++k) {
                float4 xvv = *(const float4*)&x1[w][k][dg * 4];
                scv[k] += xvv.x * wv.x + xvv.y * wv.y + xvv.z * wv.z + xvv.w * wv.w;
            }
        }
        // softmax over k + weighted sum
        float m = scv[0];
#pragma unroll
        for (int k = 1; k < 16; ++k) m = fmaxf(m, scv[k]);
        float sum = 0.f, p1 = 0.f;
#pragma unroll
        for (int k = 0; k < 16; ++k) { float e = __expf(scv[k] - m); sum += e; p1 += e * col[k]; }
        p1 /= sum;
        p1b[w][c] = p1;

        if (c < OUTC) {
            float acc = bmlp[c];
#pragma unroll
            for (int d = 0; d < 64; ++d) acc += p1b[w][d] * wm[d][c];
            preout[(size_t)p * OUTC + c] = acc;
            s += acc; s2 += (double)acc * acc;
        }
    }
    if (c < OUTC) { red[w][c][0] = s; red[w][c][1] = s2; }
    __syncthreads();
    if (t < OUTC) {
        double ts = red[0][t][0], ts2 = red[0][t][1];
        for (int g = 1; g < 4; ++g) { ts += red[g][t][0]; ts2 += red[g][t][1]; }
        atomicAdd(&stats[stat_base + t], ts);
        atomicAdd(&stats[stat_base + OUTC + t], ts2);
    }
}

// ---------------- K9: final mlp2 + shortcut BN + residual leaky + transposed write ----
__global__ __launch_bounds__(256) void k_out(const float* __restrict__ pre2,
                                             const float* __restrict__ short_pre,
                                             const float* __restrict__ W2, const float* __restrict__ b2,
                                             const float* __restrict__ ss, float* __restrict__ out) {
    __shared__ __align__(16) float w2[64][128];
    __shared__ float sc2[64], sh2[64], scs[128], shs[128], bb[128];
    int t = threadIdx.x;
    int pl = t & 63, seg = t >> 6;
    for (int e = t; e < 8192; e += 256) w2[e >> 7][e & 127] = W2[e];
    if (t < 64) { sc2[t] = ss[SS_ATT2 + t]; sh2[t] = ss[SS_ATT2 + 64 + t]; }
    if (t < 128) { scs[t] = ss[SS_SHORT + t]; shs[t] = ss[SS_SHORT + 128 + t]; bb[t] = b2[t]; }
    __syncthreads();

    int p = blockIdx.x * 64 + pl;
    int b = p >> 13, n = p & 8191;
    const float* pr = pre2 + (size_t)p * 64;
    float xa[64];
#pragma unroll
    for (int c = 0; c < 64; c += 4) {
        float4 v = *(const float4*)&pr[c];
        xa[c + 0] = fmaxf(v.x * sc2[c + 0] + sh2[c + 0], 0.f);
        xa[c + 1] = fmaxf(v.y * sc2[c + 1] + sh2[c + 1], 0.f);
        xa[c + 2] = fmaxf(v.z * sc2[c + 2] + sh2[c + 2], 0.f);
        xa[c + 3] = fmaxf(v.w * sc2[c + 3] + sh2[c + 3], 0.f);
    }
    const float* shp = short_pre + (size_t)p * 128;
    int obase = seg * 32;
    for (int o = obase; o < obase + 32; o += 4) {
        float a0 = bb[o], a1 = bb[o + 1], a2 = bb[o + 2], a3 = bb[o + 3];
#pragma unroll
        for (int cc = 0; cc < 64; ++cc) {
            float4 wv = *(const float4*)&w2[cc][o];
            float x = xa[cc];
            a0 += x * wv.x; a1 += x * wv.y; a2 += x * wv.z; a3 += x * wv.w;
        }
        float4 sv = *(const float4*)&shp[o];
        float r0 = a0 + (sv.x * scs[o] + shs[o]);
        float r1 = a1 + (sv.y * scs[o + 1] + shs[o + 1]);
        float r2 = a2 + (sv.z * scs[o + 2] + shs[o + 2]);
        float r3 = a3 + (sv.w * scs[o + 3] + shs[o + 3]);
        out[((size_t)(b * C2 + o + 0)) * NN + n] = r0 >= 0.f ? r0 : 0.01f * r0;
        out[((size_t)(b * C2 + o + 1)) * NN + n] = r1 >= 0.f ? r1 : 0.01f * r1;
        out[((size_t)(b * C2 + o + 2)) * NN + n] = r2 >= 0.f ? r2 : 0.01f * r2;
        out[((size_t)(b * C2 + o + 3)) * NN + n] = r3 >= 0.f ? r3 : 0.01f * r3;
    }
}

extern "C" void kernel_launch(void* const* d_in, const int* in_sizes, int n_in,
                              void* d_out, int out_size, void* d_ws, size_t ws_size,
                              hipStream_t stream) {
    const float* coords    = (const float*)d_in[0];
    const float* features  = (const float*)d_in[1];
    const float* W_mlp1    = (const float*)d_in[2];
    const float* b_mlp1    = (const float*)d_in[3];
    const float* W_lse1    = (const float*)d_in[4];
    const float* b_lse1    = (const float*)d_in[5];
    const float* g_lse1    = (const float*)d_in[6];
    const float* be_lse1   = (const float*)d_in[7];
    const float* W_att1_lin= (const float*)d_in[8];
    const float* W_att1_mlp= (const float*)d_in[9];
    const float* b_att1_mlp= (const float*)d_in[10];
    const float* g_att1    = (const float*)d_in[11];
    const float* be_att1   = (const float*)d_in[12];
    const float* W_lse2    = (const float*)d_in[13];
    const float* b_lse2    = (const float*)d_in[14];
    const float* g_lse2    = (const float*)d_in[15];
    const float* be_lse2   = (const float*)d_in[16];
    const float* W_att2_lin= (const float*)d_in[17];
    const float* W_att2_mlp= (const float*)d_in[18];
    const float* b_att2_mlp= (const float*)d_in[19];
    const float* g_att2    = (const float*)d_in[20];
    const float* be_att2   = (const float*)d_in[21];
    const float* W_mlp2    = (const float*)d_in[22];
    const float* b_mlp2    = (const float*)d_in[23];
    const float* W_short   = (const float*)d_in[24];
    const float* b_short   = (const float*)d_in[25];
    const float* g_short   = (const float*)d_in[26];
    const float* be_short  = (const float*)d_in[27];

    float* ws = (float*)d_ws;
    float4* cp4      = (float4*)(ws + OFF_CP4);
    float* se        = ws + OFF_SE;
    float* xf        = ws + OFF_XF;
    float* short_pre = ws + OFF_SHORT;
    float* pre1      = ws + OFF_PRE1;
    float* pre2      = ws + OFF_PRE2;
    float* ss        = ws + OFF_SS;
    double* stats    = (double*)(ws + OFF_STATS);
    float* out       = (float*)d_out;

    hipMemsetAsync(stats, 0, S_TOTAL * sizeof(double), stream);

    k_prep<<<BNTOT / 256, 256, 0, stream>>>(coords, cp4);
    k_knn<<<512, 256, 0, stream>>>(cp4, se);
    k_feat<<<512, 128, 0, stream>>>(features, W_mlp1, b_mlp1, W_short, b_short,
                                    xf, short_pre, stats);
    k_lse_stats<<<512, 256, 0, stream>>>(se, W_lse1, b_lse1, W_lse2, b_lse2, stats);
    k_fin_misc<<<1, 192, 0, stream>>>(stats, ss, g_lse1, be_lse1, g_lse2, be_lse2,
                                      g_short, be_short);
    k_att<32, false><<<512, 256, 0, stream>>>(se, xf, W_lse1, b_lse1, W_att1_lin,
                                              W_att1_mlp, b_att1_mlp, ss,
                                              SS_LSE1, 0, S_ATT1, pre1, stats);
    k_fin_att<<<1, 64, 0, stream>>>(stats, ss, g_att1, be_att1, S_ATT1, 32, SS_ATT1);
    k_att<64, true><<<512, 256, 0, stream>>>(se, pre1, W_lse2, b_lse2, W_att2_lin,
                                             W_att2_mlp, b_att2_mlp, ss,
                                             SS_LSE2, SS_ATT1, S_ATT2, pre2, stats);
    k_fin_att<<<1, 64, 0, stream>>>(stats, ss, g_att2, be_att2, S_ATT2, 64, SS_ATT2);
    k_out<<<BNTOT / 64, 256, 0, stream>>>(pre2, short_pre, W_mlp2, b_mlp2, ss, out);
}